// Round 9
// baseline (1024.435 us; speedup 1.0000x reference)
//
#include <hip/hip_runtime.h>
#include <hip/hip_bf16.h>
#include <cfloat>

typedef __attribute__((ext_vector_type(8))) short bf16x8;
typedef __attribute__((ext_vector_type(4))) float f32x4;

#define M_DIM 8192
#define N_DIM 4096
#define K_DIM 4096

__device__ inline ushort f2bf(float f) {
    unsigned u = __float_as_uint(f);
    unsigned r = (u + 0x7FFFu + ((u >> 16) & 1u)) >> 16;
    return (ushort)r;
}

// swizzle: XOR 16B-slot index (bits 4-6) with row low bits (bits 7-9). Involution.
#define SWZ(x) ((x) ^ ((((x) >> 7) & 7) << 4))

// ---------------- kernel 1: weight 4-bit group-128 qdq -> bf16, PACKED frag layout ----
// wq layout: [nb(16)][wn(4)][T(64)][kk(2)][ni(4)][lane(64)][8 elems]
// so a GEMM wave reads its B-quarter for one K-tile as 8 coalesced 1KB b128 loads.
// Block: 64 rows x 128 k (one quant group per row). Thread t: row t>>2, k-quarter t&3.
__global__ __launch_bounds__(256) void w_dq_pack(const float* __restrict__ w,
                                                 ushort* __restrict__ wq) {
    int bx = blockIdx.x;                 // 64 row-blocks * 32 k-groups = 2048
    int n0 = (bx >> 5) * 64;
    int kg = bx & 31;
    int t = threadIdx.x;
    int n = n0 + (t >> 2);
    int kq = t & 3;
    const float* src = w + (size_t)n * K_DIM + kg * 128 + kq * 32;
    float4 v[8];
    float mn = FLT_MAX, mx = -FLT_MAX;
#pragma unroll
    for (int j = 0; j < 8; j++) {
        v[j] = ((const float4*)src)[j];
        mn = fminf(mn, fminf(fminf(v[j].x, v[j].y), fminf(v[j].z, v[j].w)));
        mx = fmaxf(mx, fmaxf(fmaxf(v[j].x, v[j].y), fmaxf(v[j].z, v[j].w)));
    }
    // reduce across the 4 threads of this row (quad): lanes l, l^1, l^2 same quad
    mn = fminf(mn, __shfl_xor(mn, 1)); mx = fmaxf(mx, __shfl_xor(mx, 1));
    mn = fminf(mn, __shfl_xor(mn, 2)); mx = fmaxf(mx, __shfl_xor(mx, 2));
    float scale = (mx - mn) / 15.0f;
    float zero  = -8.0f - rintf(mn / scale);

    int nb = n >> 8, wn = (n >> 6) & 3, ni = (n >> 4) & 3, lr = n & 15;
    int T = kg * 2 + (kq >> 1), kk = kq & 1;
    size_t base16 = ((((size_t)(nb * 4 + wn) * 64 + T) * 2 + kk) * 4 + ni) * 64;
#pragma unroll
    for (int lh = 0; lh < 4; lh++) {
        bf16x8 o;
#pragma unroll
        for (int e = 0; e < 8; e++) {
            float4 vv = v[lh * 2 + (e >> 2)];
            float x = (e & 3) == 0 ? vv.x : (e & 3) == 1 ? vv.y : (e & 3) == 2 ? vv.z : vv.w;
            float q = fminf(fmaxf(rintf(x / scale) + zero, -8.0f), 7.0f);
            o[e] = (short)f2bf((q - zero) * scale);
        }
        *(bf16x8*)(wq + (base16 + lh * 16 + lr) * 8) = o;
    }
}

// ---------------- kernel 2: per-row int8 act quant-dequant -> bf16 (row-major) --------
__global__ __launch_bounds__(256) void act_qdq(const float* __restrict__ x,
                                               ushort* __restrict__ xq) {
    __shared__ float smn[4], smx[4];
    int row = blockIdx.x;
    const float* xr = x + (size_t)row * K_DIM;
    ushort* xo = xq + (size_t)row * K_DIM;
    int t = threadIdx.x;
    float4 v[4];
    float mn = FLT_MAX, mx = -FLT_MAX;
#pragma unroll
    for (int i = 0; i < 4; i++) {
        v[i] = ((const float4*)xr)[t + i * 256];
        mn = fminf(mn, fminf(fminf(v[i].x, v[i].y), fminf(v[i].z, v[i].w)));
        mx = fmaxf(mx, fmaxf(fmaxf(v[i].x, v[i].y), fmaxf(v[i].z, v[i].w)));
    }
#pragma unroll
    for (int s = 1; s < 64; s <<= 1) {
        mn = fminf(mn, __shfl_xor(mn, s));
        mx = fmaxf(mx, __shfl_xor(mx, s));
    }
    int w = t >> 6;
    if ((t & 63) == 0) { smn[w] = mn; smx[w] = mx; }
    __syncthreads();
    mn = fminf(fminf(smn[0], smn[1]), fminf(smn[2], smn[3]));
    mx = fmaxf(fmaxf(smx[0], smx[1]), fmaxf(smx[2], smx[3]));
    float scale = (mx - mn) / 255.0f;
    float zero  = -128.0f - rintf(mn / scale);
#pragma unroll
    for (int i = 0; i < 4; i++) {
        ushort4 o;
        float q;
        q = fminf(fmaxf(rintf(v[i].x / scale) + zero, -128.0f), 127.0f); o.x = f2bf((q - zero) * scale);
        q = fminf(fmaxf(rintf(v[i].y / scale) + zero, -128.0f), 127.0f); o.y = f2bf((q - zero) * scale);
        q = fminf(fmaxf(rintf(v[i].z / scale) + zero, -128.0f), 127.0f); o.z = f2bf((q - zero) * scale);
        q = fminf(fmaxf(rintf(v[i].w / scale) + zero, -128.0f), 127.0f); o.w = f2bf((q - zero) * scale);
        ((ushort4*)xo)[t + i * 256] = o;
    }
}

// ---------------- kernel 3: 256x256 bf16 GEMM; A via LDS, B direct from packed global --
// LDS was the bound (256KB/K-tile/CU demand vs MFMA 2061cyc). B now bypasses LDS:
// per-wave 8 coalesced b128 loads/K-tile from the packed layout (register dbuf).
// LDS carries A only (160KB/K-tile incl stage-writes). One barrier + vmcnt(8)/K-tile.
#define BM 256
#define BN 256
#define BK 64
#define NT (K_DIM / BK)   /* 64 K-tiles */

__global__ __launch_bounds__(512, 1) void gemm_bt8(const ushort* __restrict__ A,
                                                   const ushort* __restrict__ Bp,
                                                   float* __restrict__ C) {
    __shared__ __align__(16) ushort As[2][BM * BK];   // 2 x 32 KiB, quarter rq at byte rq*8192

    // XCD-partitioned swizzle: XCD x owns mb in [4x, 4x+4); nb varies slowly within XCD.
    int orig = blockIdx.x;
    int xcd = orig & 7, j = orig >> 3;          // 512 blocks: j in 0..63
    int mb = xcd * 4 + (j & 3);                 // 0..31
    int nb = j >> 2;                            // 0..15
    size_t m0 = (size_t)mb * BM;

    const int t = threadIdx.x;
    const int w = t >> 6, lane = t & 63;
    const int wm = w >> 2, wn = w & 3;          // 2 x 4 wave grid; per-wave out 128x64
    const int lr = lane & 15;
    const int lk = (lane >> 4) << 3;

    const ushort* Ab = A + m0 * K_DIM;
    const ushort* Bpk = Bp + (size_t)(nb * 4 + wn) * 64 * 4096;  // [T][kk][ni][l][8]

    f32x4 acc[8][4] = {};
    bf16x8 afr[4][2];      // single set, reused for each half (mi 0-3, then 4-7)
    bf16x8 bfr[2][4][2];   // [buffer parity][ni][kk], loaded direct from global

#define STAGEALL(dd, T) do {                                                      \
    _Pragma("unroll") for (int rq = 0; rq < 4; rq++) {                            \
        int base = rq * 8192 + w * 1024;                                          \
        int lb = base + lane * 16;                                                \
        int lg = SWZ(lb);                                                         \
        __builtin_amdgcn_global_load_lds(                                         \
            (const __attribute__((address_space(1))) unsigned int*)(Ab + (size_t)(lg >> 7) * K_DIM + (T) * BK + ((lg & 127) >> 1)), \
            (__attribute__((address_space(3))) unsigned int*)((char*)As[dd] + base), \
            16, 0, 0);                                                            \
    } } while (0)

#define LOADA_H(h, dd) do {                                                       \
    _Pragma("unroll") for (int mf = 0; mf < 4; mf++)                              \
    _Pragma("unroll") for (int kk = 0; kk < 2; kk++) {                            \
        int mi = (h) * 4 + mf;                                                    \
        int row = (mi >> 1) * 64 + wm * 32 + (mi & 1) * 16 + lr;                  \
        int lg = row * 128 + (kk * 32 + lk) * 2;                                  \
        afr[mf][kk] = *(const bf16x8*)((const char*)As[dd] + SWZ(lg));            \
    } } while (0)

#define LOADBG(dd, T) do {                                                        \
    const ushort* bp = Bpk + (size_t)(T) * 4096;                                  \
    _Pragma("unroll") for (int kk = 0; kk < 2; kk++)                              \
    _Pragma("unroll") for (int ni = 0; ni < 4; ni++)                              \
        bfr[dd][ni][kk] = *(const bf16x8*)(bp + ((kk * 4 + ni) * 64 + lane) * 8); \
    } while (0)

#define MFMAH(h, dd) do {                                                         \
    __builtin_amdgcn_s_setprio(1);                                                \
    _Pragma("unroll") for (int kk = 0; kk < 2; kk++)                              \
    _Pragma("unroll") for (int mf = 0; mf < 4; mf++)                              \
    _Pragma("unroll") for (int ni = 0; ni < 4; ni++)                              \
        acc[(h) * 4 + mf][ni] = __builtin_amdgcn_mfma_f32_16x16x32_bf16(          \
            afr[mf][kk], bfr[dd][ni][kk], acc[(h) * 4 + mf][ni], 0, 0, 0);        \
    __builtin_amdgcn_s_setprio(0);                                                \
  } while (0)

#define ITER(d, T) do {                                                           \
    if ((T) + 1 < NT) STAGEALL((d) ^ 1, (T) + 1);                                 \
    LOADA_H(0, d);                                                                \
    if ((T) + 1 < NT) LOADBG((d) ^ 1, (T) + 1);                                   \
    asm volatile("s_waitcnt lgkmcnt(0)" ::: "memory");                            \
    __builtin_amdgcn_sched_barrier(0);                                            \
    MFMAH(0, d);                                                                  \
    LOADA_H(1, d);                                                                \
    asm volatile("s_waitcnt lgkmcnt(0)" ::: "memory");                            \
    __builtin_amdgcn_sched_barrier(0);                                            \
    MFMAH(1, d);                                                                  \
    asm volatile("s_waitcnt vmcnt(8)" ::: "memory");                              \
    __builtin_amdgcn_s_barrier();                                                 \
    __builtin_amdgcn_sched_barrier(0);                                            \
  } while (0)

    // prologue: stage A(0), load B(0) frags, drain, sync
    STAGEALL(0, 0);
    LOADBG(0, 0);
    asm volatile("s_waitcnt vmcnt(0)" ::: "memory");
    __builtin_amdgcn_s_barrier();
    __builtin_amdgcn_sched_barrier(0);

#pragma unroll 1
    for (int i = 0; i < NT / 2; i++) {
        ITER(0, 2 * i);
        ITER(1, 2 * i + 1);
    }
#undef ITER
#undef MFMAH
#undef LOADBG
#undef LOADA_H
#undef STAGEALL

    // C write: acc[mi][ni] -> row = m0 + (mi>>1)*64 + wm*32 + (mi&1)*16 + fq*4 + r
    size_t n0 = (size_t)nb * BN;
    int fq = lane >> 4;
#pragma unroll
    for (int mi = 0; mi < 8; mi++) {
#pragma unroll
        for (int ni = 0; ni < 4; ni++) {
#pragma unroll
            for (int r = 0; r < 4; r++) {
                size_t crow = m0 + (mi >> 1) * 64 + wm * 32 + (mi & 1) * 16 + fq * 4 + r;
                C[crow * N_DIM + n0 + wn * 64 + ni * 16 + lr] = acc[mi][ni][r];
            }
        }
    }
}

extern "C" void kernel_launch(void* const* d_in, const int* in_sizes, int n_in,
                              void* d_out, int out_size, void* d_ws, size_t ws_size,
                              hipStream_t stream) {
    const float* x = (const float*)d_in[0];
    const float* w = (const float*)d_in[1];
    float* out = (float*)d_out;

    ushort* wq = (ushort*)d_ws;                                        // 32 MiB (packed)
    ushort* xq = (ushort*)((char*)d_ws + (size_t)N_DIM * K_DIM * 2);   // 64 MiB

    hipLaunchKernelGGL(w_dq_pack, dim3((N_DIM / 64) * (K_DIM / 128)), dim3(256), 0, stream, w, wq);
    hipLaunchKernelGGL(act_qdq, dim3(M_DIM), dim3(256), 0, stream, x, xq);
    hipLaunchKernelGGL(gemm_bt8, dim3((M_DIM / BM) * (N_DIM / BN)), dim3(512), 0, stream, xq, wq, out);
}

// Round 10
// 1005.661 us; speedup vs baseline: 1.0187x; 1.0187x over previous
//
#include <hip/hip_runtime.h>
#include <hip/hip_bf16.h>
#include <cfloat>

typedef __attribute__((ext_vector_type(8))) short bf16x8;
typedef __attribute__((ext_vector_type(4))) float f32x4;

#define M_DIM 8192
#define N_DIM 4096
#define K_DIM 4096

__device__ inline ushort f2bf(float f) {
    unsigned u = __float_as_uint(f);
    unsigned r = (u + 0x7FFFu + ((u >> 16) & 1u)) >> 16;
    return (ushort)r;
}

// swizzle: XOR 16B-slot index (bits 4-6) with row low bits (bits 7-9). Involution.
#define SWZ(x) ((x) ^ ((((x) >> 7) & 7) << 4))

// ---------------- kernel 1: weight 4-bit group-128 qdq -> bf16, PACKED frag layout ----
// wq layout: [nb(16)][wn(4)][T(64)][kk(2)][ni(4)][lane(64)][8 elems]
__global__ __launch_bounds__(256) void w_dq_pack(const float* __restrict__ w,
                                                 ushort* __restrict__ wq) {
    int bx = blockIdx.x;                 // 64 row-blocks * 32 k-groups = 2048
    int n0 = (bx >> 5) * 64;
    int kg = bx & 31;
    int t = threadIdx.x;
    int n = n0 + (t >> 2);
    int kq = t & 3;
    const float* src = w + (size_t)n * K_DIM + kg * 128 + kq * 32;
    float4 v[8];
    float mn = FLT_MAX, mx = -FLT_MAX;
#pragma unroll
    for (int j = 0; j < 8; j++) {
        v[j] = ((const float4*)src)[j];
        mn = fminf(mn, fminf(fminf(v[j].x, v[j].y), fminf(v[j].z, v[j].w)));
        mx = fmaxf(mx, fmaxf(fmaxf(v[j].x, v[j].y), fmaxf(v[j].z, v[j].w)));
    }
    mn = fminf(mn, __shfl_xor(mn, 1)); mx = fmaxf(mx, __shfl_xor(mx, 1));
    mn = fminf(mn, __shfl_xor(mn, 2)); mx = fmaxf(mx, __shfl_xor(mx, 2));
    float scale = (mx - mn) / 15.0f;
    float zero  = -8.0f - rintf(mn / scale);

    int nb = n >> 8, wn = (n >> 6) & 3, ni = (n >> 4) & 3, lr = n & 15;
    int T = kg * 2 + (kq >> 1), kk = kq & 1;
    size_t base16 = ((((size_t)(nb * 4 + wn) * 64 + T) * 2 + kk) * 4 + ni) * 64;
#pragma unroll
    for (int lh = 0; lh < 4; lh++) {
        bf16x8 o;
#pragma unroll
        for (int e = 0; e < 8; e++) {
            float4 vv = v[lh * 2 + (e >> 2)];
            float x = (e & 3) == 0 ? vv.x : (e & 3) == 1 ? vv.y : (e & 3) == 2 ? vv.z : vv.w;
            float q = fminf(fmaxf(rintf(x / scale) + zero, -8.0f), 7.0f);
            o[e] = (short)f2bf((q - zero) * scale);
        }
        *(bf16x8*)(wq + (base16 + lh * 16 + lr) * 8) = o;
    }
}

// ---------------- kernel 2: per-row int8 act quant-dequant -> bf16 (row-major) --------
__global__ __launch_bounds__(256) void act_qdq(const float* __restrict__ x,
                                               ushort* __restrict__ xq) {
    __shared__ float smn[4], smx[4];
    int row = blockIdx.x;
    const float* xr = x + (size_t)row * K_DIM;
    ushort* xo = xq + (size_t)row * K_DIM;
    int t = threadIdx.x;
    float4 v[4];
    float mn = FLT_MAX, mx = -FLT_MAX;
#pragma unroll
    for (int i = 0; i < 4; i++) {
        v[i] = ((const float4*)xr)[t + i * 256];
        mn = fminf(mn, fminf(fminf(v[i].x, v[i].y), fminf(v[i].z, v[i].w)));
        mx = fmaxf(mx, fmaxf(fmaxf(v[i].x, v[i].y), fmaxf(v[i].z, v[i].w)));
    }
#pragma unroll
    for (int s = 1; s < 64; s <<= 1) {
        mn = fminf(mn, __shfl_xor(mn, s));
        mx = fmaxf(mx, __shfl_xor(mx, s));
    }
    int w = t >> 6;
    if ((t & 63) == 0) { smn[w] = mn; smx[w] = mx; }
    __syncthreads();
    mn = fminf(fminf(smn[0], smn[1]), fminf(smn[2], smn[3]));
    mx = fmaxf(fmaxf(smx[0], smx[1]), fmaxf(smx[2], smx[3]));
    float scale = (mx - mn) / 255.0f;
    float zero  = -128.0f - rintf(mn / scale);
#pragma unroll
    for (int i = 0; i < 4; i++) {
        ushort4 o;
        float q;
        q = fminf(fmaxf(rintf(v[i].x / scale) + zero, -128.0f), 127.0f); o.x = f2bf((q - zero) * scale);
        q = fminf(fmaxf(rintf(v[i].y / scale) + zero, -128.0f), 127.0f); o.y = f2bf((q - zero) * scale);
        q = fminf(fmaxf(rintf(v[i].z / scale) + zero, -128.0f), 127.0f); o.z = f2bf((q - zero) * scale);
        q = fminf(fmaxf(rintf(v[i].w / scale) + zero, -128.0f), 127.0f); o.w = f2bf((q - zero) * scale);
        ((ushort4*)xo)[t + i * 256] = o;
    }
}

// ---------------- kernel 3: 256x256 bf16 GEMM; A via LDS, B direct from packed global --
// L2-stripe swizzle: each XCD's 32 concurrent blocks share ONE nb column (2MB of packed
// B <= 4MB L2). B loads issued one full K-tile ahead -> L2 latency hidden. LDS carries
// A only (160KB/K-tile < MFMA 2483cyc -> MFMA-bound target).
#define BM 256
#define BN 256
#define BK 64
#define NT (K_DIM / BK)   /* 64 K-tiles */

__global__ __launch_bounds__(512, 1) void gemm_bt8(const ushort* __restrict__ A,
                                                   const ushort* __restrict__ Bp,
                                                   float* __restrict__ C) {
    __shared__ __align__(16) ushort As[2][BM * BK];   // 2 x 32 KiB, quarter rq at byte rq*8192

    // stripe swizzle: xcd = orig&7 owns nb in {2*xcd, 2*xcd+1}; concurrent j<32 share nb.
    int orig = blockIdx.x;
    int xcd = orig & 7, j = orig >> 3;          // j in 0..63
    int nb = xcd * 2 + (j >> 5);                // 0..15
    int mb = j & 31;                            // 0..31
    size_t m0 = (size_t)mb * BM;

    const int t = threadIdx.x;
    const int w = t >> 6, lane = t & 63;
    const int wm = w >> 2, wn = w & 3;          // 2 x 4 wave grid; per-wave out 128x64
    const int lr = lane & 15;
    const int lk = (lane >> 4) << 3;

    const ushort* Ab = A + m0 * K_DIM;
    const ushort* Bpk = Bp + (size_t)(nb * 4 + wn) * 64 * 4096;  // [T][kk][ni][l][8]

    f32x4 acc[8][4] = {};
    bf16x8 afr[4][2];      // single set, reused for each half (HW scoreboard covers WAR)
    bf16x8 bfr[2][4][2];   // [buffer parity][ni][kk], direct from global (L2-resident)

#define STAGEALL(dd, T) do {                                                      \
    _Pragma("unroll") for (int rq = 0; rq < 4; rq++) {                            \
        int base = rq * 8192 + w * 1024;                                          \
        int lb = base + lane * 16;                                                \
        int lg = SWZ(lb);                                                         \
        __builtin_amdgcn_global_load_lds(                                         \
            (const __attribute__((address_space(1))) unsigned int*)(Ab + (size_t)(lg >> 7) * K_DIM + (T) * BK + ((lg & 127) >> 1)), \
            (__attribute__((address_space(3))) unsigned int*)((char*)As[dd] + base), \
            16, 0, 0);                                                            \
    } } while (0)

#define LOADA_H(h, dd) do {                                                       \
    _Pragma("unroll") for (int mf = 0; mf < 4; mf++)                              \
    _Pragma("unroll") for (int kk = 0; kk < 2; kk++) {                            \
        int mi = (h) * 4 + mf;                                                    \
        int row = (mi >> 1) * 64 + wm * 32 + (mi & 1) * 16 + lr;                  \
        int lg = row * 128 + (kk * 32 + lk) * 2;                                  \
        afr[mf][kk] = *(const bf16x8*)((const char*)As[dd] + SWZ(lg));            \
    } } while (0)

#define LOADBG(dd, T) do {                                                        \
    const ushort* bp = Bpk + (size_t)(T) * 4096;                                  \
    _Pragma("unroll") for (int kk = 0; kk < 2; kk++)                              \
    _Pragma("unroll") for (int ni = 0; ni < 4; ni++)                              \
        bfr[dd][ni][kk] = *(const bf16x8*)(bp + ((kk * 4 + ni) * 64 + lane) * 8); \
    } while (0)

#define MFMAH(h, dd) do {                                                         \
    __builtin_amdgcn_s_setprio(1);                                                \
    _Pragma("unroll") for (int kk = 0; kk < 2; kk++)                              \
    _Pragma("unroll") for (int mf = 0; mf < 4; mf++)                              \
    _Pragma("unroll") for (int ni = 0; ni < 4; ni++)                              \
        acc[(h) * 4 + mf][ni] = __builtin_amdgcn_mfma_f32_16x16x32_bf16(          \
            afr[mf][kk], bfr[dd][ni][kk], acc[(h) * 4 + mf][ni], 0, 0, 0);        \
    __builtin_amdgcn_s_setprio(0);                                                \
  } while (0)

#define ITER(d, T) do {                                                           \
    if ((T) + 1 < NT) STAGEALL((d) ^ 1, (T) + 1);                                 \
    LOADA_H(0, d);                                                                \
    if ((T) + 1 < NT) LOADBG((d) ^ 1, (T) + 1);                                   \
    asm volatile("s_waitcnt lgkmcnt(0)" ::: "memory");                            \
    __builtin_amdgcn_sched_barrier(0);                                            \
    MFMAH(0, d);                                                                  \
    LOADA_H(1, d);                                                                \
    asm volatile("s_waitcnt lgkmcnt(0)" ::: "memory");                            \
    __builtin_amdgcn_sched_barrier(0);                                            \
    MFMAH(1, d);                                                                  \
    asm volatile("s_waitcnt vmcnt(8)" ::: "memory");                              \
    __builtin_amdgcn_s_barrier();                                                 \
    __builtin_amdgcn_sched_barrier(0);                                            \
  } while (0)

    // prologue: stage A(0), load B(0) frags, drain, sync
    STAGEALL(0, 0);
    LOADBG(0, 0);
    asm volatile("s_waitcnt vmcnt(0)" ::: "memory");
    __builtin_amdgcn_s_barrier();
    __builtin_amdgcn_sched_barrier(0);

#pragma unroll 1
    for (int i = 0; i < NT / 2; i++) {
        ITER(0, 2 * i);
        ITER(1, 2 * i + 1);
    }
#undef ITER
#undef MFMAH
#undef LOADBG
#undef LOADA_H
#undef STAGEALL

    // C write: acc[mi][ni] -> row = m0 + (mi>>1)*64 + wm*32 + (mi&1)*16 + fq*4 + r
    size_t n0 = (size_t)nb * BN;
    int fq = lane >> 4;
#pragma unroll
    for (int mi = 0; mi < 8; mi++) {
#pragma unroll
        for (int ni = 0; ni < 4; ni++) {
#pragma unroll
            for (int r = 0; r < 4; r++) {
                size_t crow = m0 + (mi >> 1) * 64 + wm * 32 + (mi & 1) * 16 + fq * 4 + r;
                C[crow * N_DIM + n0 + wn * 64 + ni * 16 + lr] = acc[mi][ni][r];
            }
        }
    }
}

extern "C" void kernel_launch(void* const* d_in, const int* in_sizes, int n_in,
                              void* d_out, int out_size, void* d_ws, size_t ws_size,
                              hipStream_t stream) {
    const float* x = (const float*)d_in[0];
    const float* w = (const float*)d_in[1];
    float* out = (float*)d_out;

    ushort* wq = (ushort*)d_ws;                                        // 32 MiB (packed)
    ushort* xq = (ushort*)((char*)d_ws + (size_t)N_DIM * K_DIM * 2);   // 64 MiB

    hipLaunchKernelGGL(w_dq_pack, dim3((N_DIM / 64) * (K_DIM / 128)), dim3(256), 0, stream, w, wq);
    hipLaunchKernelGGL(act_qdq, dim3(M_DIM), dim3(256), 0, stream, x, xq);
    hipLaunchKernelGGL(gemm_bt8, dim3((M_DIM / BM) * (N_DIM / BN)), dim3(512), 0, stream, xq, wq, out);
}

// Round 11
// 354.903 us; speedup vs baseline: 2.8865x; 2.8336x over previous
//
#include <hip/hip_runtime.h>
#include <hip/hip_bf16.h>
#include <cfloat>

typedef __attribute__((ext_vector_type(8))) short bf16x8;
typedef __attribute__((ext_vector_type(4))) float f32x4;

#define M_DIM 8192
#define N_DIM 4096
#define K_DIM 4096

__device__ inline ushort f2bf(float f) {
    unsigned u = __float_as_uint(f);
    unsigned r = (u + 0x7FFFu + ((u >> 16) & 1u)) >> 16;
    return (ushort)r;
}

// swizzle: XOR 16B-slot index (bits 4-6) with row low bits (bits 7-9). Involution.
#define SWZ(x) ((x) ^ ((((x) >> 7) & 7) << 4))

// ---------------- kernel 1: weight 4-bit group-128 qdq -> bf16, PACKED frag layout ----
// wq layout: [nb(16)][wn(4)][T(64)][kk(2)][ni(4)][lane(64)][8 elems]
__global__ __launch_bounds__(256) void w_dq_pack(const float* __restrict__ w,
                                                 ushort* __restrict__ wq) {
    int bx = blockIdx.x;                 // 64 row-blocks * 32 k-groups = 2048
    int n0 = (bx >> 5) * 64;
    int kg = bx & 31;
    int t = threadIdx.x;
    int n = n0 + (t >> 2);
    int kq = t & 3;
    const float* src = w + (size_t)n * K_DIM + kg * 128 + kq * 32;
    float4 v[8];
    float mn = FLT_MAX, mx = -FLT_MAX;
#pragma unroll
    for (int j = 0; j < 8; j++) {
        v[j] = ((const float4*)src)[j];
        mn = fminf(mn, fminf(fminf(v[j].x, v[j].y), fminf(v[j].z, v[j].w)));
        mx = fmaxf(mx, fmaxf(fmaxf(v[j].x, v[j].y), fmaxf(v[j].z, v[j].w)));
    }
    mn = fminf(mn, __shfl_xor(mn, 1)); mx = fmaxf(mx, __shfl_xor(mx, 1));
    mn = fminf(mn, __shfl_xor(mn, 2)); mx = fmaxf(mx, __shfl_xor(mx, 2));
    float scale = (mx - mn) / 15.0f;
    float zero  = -8.0f - rintf(mn / scale);

    int nb = n >> 8, wn = (n >> 6) & 3, ni = (n >> 4) & 3, lr = n & 15;
    int T = kg * 2 + (kq >> 1), kk = kq & 1;
    size_t base16 = ((((size_t)(nb * 4 + wn) * 64 + T) * 2 + kk) * 4 + ni) * 64;
#pragma unroll
    for (int lh = 0; lh < 4; lh++) {
        bf16x8 o;
#pragma unroll
        for (int e = 0; e < 8; e++) {
            float4 vv = v[lh * 2 + (e >> 2)];
            float x = (e & 3) == 0 ? vv.x : (e & 3) == 1 ? vv.y : (e & 3) == 2 ? vv.z : vv.w;
            float q = fminf(fmaxf(rintf(x / scale) + zero, -8.0f), 7.0f);
            o[e] = (short)f2bf((q - zero) * scale);
        }
        *(bf16x8*)(wq + (base16 + lh * 16 + lr) * 8) = o;
    }
}

// ---------------- kernel 2: per-row int8 act quant-dequant -> bf16 (row-major) --------
__global__ __launch_bounds__(256) void act_qdq(const float* __restrict__ x,
                                               ushort* __restrict__ xq) {
    __shared__ float smn[4], smx[4];
    int row = blockIdx.x;
    const float* xr = x + (size_t)row * K_DIM;
    ushort* xo = xq + (size_t)row * K_DIM;
    int t = threadIdx.x;
    float4 v[4];
    float mn = FLT_MAX, mx = -FLT_MAX;
#pragma unroll
    for (int i = 0; i < 4; i++) {
        v[i] = ((const float4*)xr)[t + i * 256];
        mn = fminf(mn, fminf(fminf(v[i].x, v[i].y), fminf(v[i].z, v[i].w)));
        mx = fmaxf(mx, fmaxf(fmaxf(v[i].x, v[i].y), fmaxf(v[i].z, v[i].w)));
    }
#pragma unroll
    for (int s = 1; s < 64; s <<= 1) {
        mn = fminf(mn, __shfl_xor(mn, s));
        mx = fmaxf(mx, __shfl_xor(mx, s));
    }
    int w = t >> 6;
    if ((t & 63) == 0) { smn[w] = mn; smx[w] = mx; }
    __syncthreads();
    mn = fminf(fminf(smn[0], smn[1]), fminf(smn[2], smn[3]));
    mx = fmaxf(fmaxf(smx[0], smx[1]), fmaxf(smx[2], smx[3]));
    float scale = (mx - mn) / 255.0f;
    float zero  = -128.0f - rintf(mn / scale);
#pragma unroll
    for (int i = 0; i < 4; i++) {
        ushort4 o;
        float q;
        q = fminf(fmaxf(rintf(v[i].x / scale) + zero, -128.0f), 127.0f); o.x = f2bf((q - zero) * scale);
        q = fminf(fmaxf(rintf(v[i].y / scale) + zero, -128.0f), 127.0f); o.y = f2bf((q - zero) * scale);
        q = fminf(fmaxf(rintf(v[i].z / scale) + zero, -128.0f), 127.0f); o.z = f2bf((q - zero) * scale);
        q = fminf(fmaxf(rintf(v[i].w / scale) + zero, -128.0f), 127.0f); o.w = f2bf((q - zero) * scale);
        ((ushort4*)xo)[t + i * 256] = o;
    }
}

// ---------------- kernel 3: 256x256 bf16 GEMM; A via LDS, B direct (single-buffer) ----
// Spill fix: bfr single-buffered (32 VGPR). B-loads for tile T issued FIRST in ITER(T)
// (oldest in vm queue) -> compiler's pre-MFMA vmcnt drains only them, after the
// ds_read+lgkm window covers L2 latency. Stages(T+1) drain at iter end (vmcnt(0), ~free).
#define BM 256
#define BN 256
#define BK 64
#define NT (K_DIM / BK)   /* 64 K-tiles */

__global__ __launch_bounds__(512, 1) void gemm_bt8(const ushort* __restrict__ A,
                                                   const ushort* __restrict__ Bp,
                                                   float* __restrict__ C) {
    __shared__ __align__(16) ushort As[2][BM * BK];   // 2 x 32 KiB, quarter rq at byte rq*8192

    // stripe swizzle: xcd = orig&7 owns nb in {2*xcd, 2*xcd+1}; concurrent j<32 share nb.
    int orig = blockIdx.x;
    int xcd = orig & 7, j = orig >> 3;          // j in 0..63
    int nb = xcd * 2 + (j >> 5);                // 0..15
    int mb = j & 31;                            // 0..31
    size_t m0 = (size_t)mb * BM;

    const int t = threadIdx.x;
    const int w = t >> 6, lane = t & 63;
    const int wm = w >> 2, wn = w & 3;          // 2 x 4 wave grid; per-wave out 128x64
    const int lr = lane & 15;
    const int lk = (lane >> 4) << 3;

    const ushort* Ab = A + m0 * K_DIM;
    const ushort* Bpk = Bp + (size_t)(nb * 4 + wn) * 64 * 4096;  // [T][kk][ni][l][8]

    f32x4 acc[8][4] = {};
    bf16x8 afr[4][2];      // single set, reused per half
    bf16x8 bfr[4][2];      // single set: current tile's B frags

#define STAGEALL(dd, T) do {                                                      \
    _Pragma("unroll") for (int rq = 0; rq < 4; rq++) {                            \
        int base = rq * 8192 + w * 1024;                                          \
        int lb = base + lane * 16;                                                \
        int lg = SWZ(lb);                                                         \
        __builtin_amdgcn_global_load_lds(                                         \
            (const __attribute__((address_space(1))) unsigned int*)(Ab + (size_t)(lg >> 7) * K_DIM + (T) * BK + ((lg & 127) >> 1)), \
            (__attribute__((address_space(3))) unsigned int*)((char*)As[dd] + base), \
            16, 0, 0);                                                            \
    } } while (0)

#define LOADA_H(h, dd) do {                                                       \
    _Pragma("unroll") for (int mf = 0; mf < 4; mf++)                              \
    _Pragma("unroll") for (int kk = 0; kk < 2; kk++) {                            \
        int mi = (h) * 4 + mf;                                                    \
        int row = (mi >> 1) * 64 + wm * 32 + (mi & 1) * 16 + lr;                  \
        int lg = row * 128 + (kk * 32 + lk) * 2;                                  \
        afr[mf][kk] = *(const bf16x8*)((const char*)As[dd] + SWZ(lg));            \
    } } while (0)

#define LOADBG(T) do {                                                            \
    const ushort* bp = Bpk + (size_t)(T) * 4096;                                  \
    _Pragma("unroll") for (int kk = 0; kk < 2; kk++)                              \
    _Pragma("unroll") for (int ni = 0; ni < 4; ni++)                              \
        bfr[ni][kk] = *(const bf16x8*)(bp + ((kk * 4 + ni) * 64 + lane) * 8);     \
    } while (0)

#define MFMAH(h) do {                                                             \
    __builtin_amdgcn_s_setprio(1);                                                \
    _Pragma("unroll") for (int kk = 0; kk < 2; kk++)                              \
    _Pragma("unroll") for (int mf = 0; mf < 4; mf++)                              \
    _Pragma("unroll") for (int ni = 0; ni < 4; ni++)                              \
        acc[(h) * 4 + mf][ni] = __builtin_amdgcn_mfma_f32_16x16x32_bf16(          \
            afr[mf][kk], bfr[ni][kk], acc[(h) * 4 + mf][ni], 0, 0, 0);            \
    __builtin_amdgcn_s_setprio(0);                                                \
  } while (0)

#define ITER(d, T) do {                                                           \
    LOADBG(T);                      /* oldest in vm queue */                      \
    if ((T) + 1 < NT) STAGEALL((d) ^ 1, (T) + 1);                                 \
    LOADA_H(0, d);                                                                \
    asm volatile("s_waitcnt lgkmcnt(0)" ::: "memory");                            \
    __builtin_amdgcn_sched_barrier(0);                                            \
    MFMAH(0);                       /* compiler inserts vmcnt for bfr here */     \
    LOADA_H(1, d);                                                                \
    asm volatile("s_waitcnt lgkmcnt(0)" ::: "memory");                            \
    __builtin_amdgcn_sched_barrier(0);                                            \
    MFMAH(1);                                                                     \
    asm volatile("s_waitcnt vmcnt(0)" ::: "memory");   /* stages ~2500cy old */   \
    __builtin_amdgcn_s_barrier();                                                 \
    __builtin_amdgcn_sched_barrier(0);                                            \
  } while (0)

    // prologue: stage A(0), drain, sync
    STAGEALL(0, 0);
    asm volatile("s_waitcnt vmcnt(0)" ::: "memory");
    __builtin_amdgcn_s_barrier();
    __builtin_amdgcn_sched_barrier(0);

#pragma unroll 1
    for (int i = 0; i < NT / 2; i++) {
        ITER(0, 2 * i);
        ITER(1, 2 * i + 1);
    }
#undef ITER
#undef MFMAH
#undef LOADBG
#undef LOADA_H
#undef STAGEALL

    // C write: acc[mi][ni] -> row = m0 + (mi>>1)*64 + wm*32 + (mi&1)*16 + fq*4 + r
    size_t n0 = (size_t)nb * BN;
    int fq = lane >> 4;
#pragma unroll
    for (int mi = 0; mi < 8; mi++) {
#pragma unroll
        for (int ni = 0; ni < 4; ni++) {
#pragma unroll
            for (int r = 0; r < 4; r++) {
                size_t crow = m0 + (mi >> 1) * 64 + wm * 32 + (mi & 1) * 16 + fq * 4 + r;
                C[crow * N_DIM + n0 + wn * 64 + ni * 16 + lr] = acc[mi][ni][r];
            }
        }
    }
}

extern "C" void kernel_launch(void* const* d_in, const int* in_sizes, int n_in,
                              void* d_out, int out_size, void* d_ws, size_t ws_size,
                              hipStream_t stream) {
    const float* x = (const float*)d_in[0];
    const float* w = (const float*)d_in[1];
    float* out = (float*)d_out;

    ushort* wq = (ushort*)d_ws;                                        // 32 MiB (packed)
    ushort* xq = (ushort*)((char*)d_ws + (size_t)N_DIM * K_DIM * 2);   // 64 MiB

    hipLaunchKernelGGL(w_dq_pack, dim3((N_DIM / 64) * (K_DIM / 128)), dim3(256), 0, stream, w, wq);
    hipLaunchKernelGGL(act_qdq, dim3(M_DIM), dim3(256), 0, stream, x, xq);
    hipLaunchKernelGGL(gemm_bt8, dim3((M_DIM / BM) * (N_DIM / BN)), dim3(512), 0, stream, xq, wq, out);
}